// Round 1
// 203.525 us; speedup vs baseline: 1.1176x; 1.1176x over previous
//
#include <hip/hip_runtime.h>
#include <hip/hip_fp16.h>

#define FEAT 32
#define BIN_NODES 128
#define BIN_SHIFT 7
#define TILE_EDGES 8192   // edges per build block
#define BWAVES 16         // waves per build block (1024 threads)
#define SRC_BITS 20
#define SRC_MASK 0xFFFFF

// Block-local int64-vs-int32 detection: odd 32-bit words of an int64 index
// array (values < 2^31) are all zero; for int32 they are random node ids.
__device__ __forceinline__ int block_detect_int64(const int* __restrict__ raw32, int* nz) {
    if (threadIdx.x == 0) *nz = 0;
    __syncthreads();
    if (raw32[2 * threadIdx.x + 1] != 0) *nz = 1;
    __syncthreads();
    return (*nz == 0) ? 1 : 0;
}

__device__ __forceinline__ int load_idx(const void* raw, int f, long long i) {
    return f ? (int)((const long long*)raw)[i] : ((const int*)raw)[i];
}

// Phase A: per-(tile,bin) histogram, 16 wave-private copies (1024 threads).
// mat layout: mat[k*nb + b] (tile-major). Writeout merges the 16 copies.
__global__ __launch_bounds__(1024)
void binA_kernel(const void* __restrict__ raw, int* __restrict__ mat, int e, int nb) {
    extern __shared__ int hist[];  // BWAVES*nb + 1
    int t = threadIdx.x;
    for (int i = t; i < BWAVES * nb; i += 1024) hist[i] = 0;
    int f = block_detect_int64((const int*)raw, &hist[BWAVES * nb]);
    int w = t >> 6, lane = t & 63;
    long long base = (long long)blockIdx.x * TILE_EDGES;
    int cnt = (int)min((long long)TILE_EDGES, (long long)e - base);
    int* hw = hist + w * nb;
    const int seg = TILE_EDGES / BWAVES;  // 512 edges per wave
    int wbeg = w * seg;
    int wend = min(wbeg + seg, cnt);
    for (int i = wbeg + lane; i < wend; i += 64) {
        int d = load_idx(raw, f, (long long)e + base + i);
        atomicAdd(&hw[d >> BIN_SHIFT], 1);
    }
    __syncthreads();
    for (int b = t; b < nb; b += 1024) {
        int s = 0;
#pragma unroll
        for (int w2 = 0; w2 < BWAVES; ++w2) s += hist[w2 * nb + b];
        mat[blockIdx.x * nb + b] = s;
    }
}

// logical L = b*nblk + k (bin-major) <-> physical p = k*nb + b
__device__ __forceinline__ int l2p(int L, int nb, int nblk) {
    int b = L / nblk;
    int k = L - b * nblk;
    return k * nb + b;
}

__global__ void scan1_kernel(int* __restrict__ mat, int* __restrict__ bsum,
                             int M, int nb, int nblk) {
    __shared__ int sd[256];
    int t = threadIdx.x;
    int L = blockIdx.x * 256 + t;
    int p = 0, v = 0;
    if (L < M) { p = l2p(L, nb, nblk); v = mat[p]; }
    sd[t] = v;
    __syncthreads();
    for (int off = 1; off < 256; off <<= 1) {
        int add = (t >= off) ? sd[t - off] : 0;
        __syncthreads();
        sd[t] += add;
        __syncthreads();
    }
    if (L < M) mat[p] = sd[t] - v;   // exclusive within scan-block
    if (t == 255) bsum[blockIdx.x] = sd[t];
}

__global__ void scan2_kernel(int* __restrict__ bsum, int nbks) {
    __shared__ int sd[1024];
    int t = threadIdx.x;
    int v = (t < nbks) ? bsum[t] : 0;
    sd[t] = v;
    __syncthreads();
    for (int off = 1; off < 1024; off <<= 1) {
        int add = (t >= off) ? sd[t - off] : 0;
        __syncthreads();
        sd[t] += add;
        __syncthreads();
    }
    if (t < nbks) bsum[t] = sd[t] - v;
}

// Phase C: scatter packed records grouped by bin (1024 threads; block-shared
// cursors — conflict cycles measured negligible). rec = src | dst_local<<20.
__global__ __launch_bounds__(1024)
void binC_kernel(const void* __restrict__ raw, const int* __restrict__ mat,
                 const int* __restrict__ bsum, int* __restrict__ packed,
                 int e, int nb, int nblk) {
    extern __shared__ int cur[];  // nb + 1
    int t = threadIdx.x;
    int f = block_detect_int64((const int*)raw, &cur[nb]);
    for (int i = t; i < nb; i += 1024)
        cur[i] = mat[blockIdx.x * nb + i] + bsum[(i * nblk + blockIdx.x) >> 8];
    __syncthreads();
    long long base = (long long)blockIdx.x * TILE_EDGES;
    int cnt = (int)min((long long)TILE_EDGES, (long long)e - base);
    for (int i = t; i < cnt; i += 1024) {
        long long ei = base + i;
        int s = load_idx(raw, f, ei);
        int d = load_idx(raw, f, (long long)e + ei);
        int b = d >> BIN_SHIFT;
        int pos = atomicAdd(&cur[b], 1);
        packed[pos] = s | ((d & (BIN_NODES - 1)) << SRC_BITS);
    }
}

// Per-bin: 16 wave-private LDS histograms -> scan -> dis/row_start + per-wave
// base cursors, then contention-free counting-sort (recs = src, 4B).
// FUSED layer-1 transform: this block owns nodes [b*128, b*128+128); after the
// sort-scatter each 8-thread group computes h1[node] = fp16(dis*(x@W1)) using
// W1 staged in LDS (x read + h1 write overlap the scatter's LDS atomics).
__global__ __launch_bounds__(1024)
void degsort_kernel(const int* __restrict__ packed, const int* __restrict__ mat,
                    const int* __restrict__ bsum, float* __restrict__ dis,
                    int* __restrict__ row_start, int* __restrict__ recs,
                    const float* __restrict__ x, const float* __restrict__ W1,
                    __half* __restrict__ h1,
                    int e, int n, int nb, int nblk) {
    __shared__ int cnt[BWAVES][BIN_NODES];
    __shared__ int wcur[BWAVES][BIN_NODES];
    __shared__ int exc[BIN_NODES];
    __shared__ float sdis[BIN_NODES];
    __shared__ float W1l[FEAT * FEAT];
    int b = blockIdx.x, t = threadIdx.x;
    int w = t >> 6;
    for (int i = t; i < BWAVES * BIN_NODES; i += 1024) ((int*)cnt)[i] = 0;
    if (t < FEAT * FEAT) W1l[t] = W1[t];   // 1024 threads, 1024 elems
    __syncthreads();
    int start = mat[b] + bsum[(b * nblk) >> 8];
    int end = (b + 1 < nb) ? (mat[b + 1] + bsum[((b + 1) * nblk) >> 8]) : e;
    for (int i = start + t; i < end; i += 1024)
        atomicAdd(&cnt[w][packed[i] >> SRC_BITS], 1);
    __syncthreads();
    if (t < BIN_NODES) {
        int s = 0;
#pragma unroll
        for (int w2 = 0; w2 < BWAVES; ++w2) s += cnt[w2][t];
        exc[t] = s;
    }
    __syncthreads();
    for (int off = 1; off < BIN_NODES; off <<= 1) {
        int v = 0;
        if (t < BIN_NODES && t >= off) v = exc[t - off];
        __syncthreads();
        if (t < BIN_NODES) exc[t] += v;
        __syncthreads();
    }
    if (t < BIN_NODES) {
        int tot = 0;
#pragma unroll
        for (int w2 = 0; w2 < BWAVES; ++w2) tot += cnt[w2][t];
        int rs = start + exc[t] - tot;   // inclusive -> exclusive
        int run = rs;
#pragma unroll
        for (int w2 = 0; w2 < BWAVES; ++w2) { wcur[w2][t] = run; run += cnt[w2][t]; }
        float dv = rsqrtf((float)tot + 1.0f);
        sdis[t] = dv;
        int node = b * BIN_NODES + t;
        if (node < n) {
            dis[node] = dv;
            row_start[node] = rs;
        }
    }
    if (b == 0 && t == 128) row_start[n] = e;  // sentinel
    __syncthreads();
    for (int i = start + t; i < end; i += 1024) {
        int rec = packed[i];
        int pos = atomicAdd(&wcur[w][rec >> SRC_BITS], 1);
        recs[pos] = rec & SRC_MASK;
    }
    // fused mm1: 8 threads/node, each thread holds one float4 of the x-row and
    // produces 4 output features; 8-wide shfl broadcasts the x values.
    {
        int ln = b * BIN_NODES + (t >> 3);
        if (ln < n) {
            int q = t & 7;
            float4 xv = ((const float4*)x)[(size_t)ln * 8 + q];
            float xr[4] = {xv.x, xv.y, xv.z, xv.w};
            float o[4] = {0.f, 0.f, 0.f, 0.f};
#pragma unroll
            for (int k = 0; k < FEAT; ++k) {
                float xk = __shfl(xr[k & 3], k >> 2, 8);
#pragma unroll
                for (int c = 0; c < 4; ++c)
                    o[c] = fmaf(xk, W1l[k * FEAT + q * 4 + c], o[c]);
            }
            float dn = sdis[t >> 3];
            __half2* hp = (__half2*)&h1[(size_t)ln * FEAT + q * 4];
            hp[0] = __halves2half2(__float2half(dn * o[0]), __float2half(dn * o[1]));
            hp[1] = __halves2half2(__float2half(dn * o[2]), __float2half(dn * o[3]));
        }
    }
}

// Layer-1 pull FUSED with layer-2 transform: gather+reduce as before; the
// xor-butterfly leaves the full reduced sums replicated in every lane of the
// 32-lane node group (per fb), so the finalized relu(out1) row lives in
// registers distributed as feature k -> lane k>>3 (canonical), reg k&7.
// A 32-step shfl+fma against W2-in-LDS yields h2 = fp16(dis*(relu(out1)@W2))
// with no acc1 round-trip and no separate matmul dispatch.
__global__ __launch_bounds__(256, 6)
void pull_mm_kernel(const int* __restrict__ recs, const int* __restrict__ row_start,
                    const __half* __restrict__ h, const float* __restrict__ dis,
                    const float* __restrict__ bias, const float* __restrict__ W2,
                    __half* __restrict__ h2, int n) {
    __shared__ float Wl[FEAT * FEAT];
    int t = threadIdx.x;
    for (int i = t; i < FEAT * FEAT; i += 256) Wl[i] = W2[i];
    __syncthreads();
    int node = blockIdx.x * 8 + (t >> 5);
    if (node >= n) return;
    int l32 = t & 31;
    int sub = l32 >> 2;   // record slot 0..7
    int fb = l32 & 3;     // float4 feature block (8 halves)
    int start = row_start[node];
    int deg = row_start[node + 1] - start;
    const float4* h4 = (const float4*)h;  // 8 halves per float4, 4 per row
    float s0 = 0, s1 = 0, s2 = 0, s3 = 0, s4 = 0, s5 = 0, s6 = 0, s7 = 0;
    for (int r0 = 0; r0 < deg; r0 += 64) {
#pragma unroll
        for (int w = 0; w < 8; ++w) {
            int r = r0 + w * 8 + sub;
            if (r < deg) {
                int s = recs[start + r];
                float4 v = h4[(size_t)s * 4 + fb];
                const __half2* hp = (const __half2*)&v;
                float2 a = __half22float2(hp[0]);
                float2 b = __half22float2(hp[1]);
                float2 c = __half22float2(hp[2]);
                float2 d = __half22float2(hp[3]);
                s0 += a.x; s1 += a.y; s2 += b.x; s3 += b.y;
                s4 += c.x; s5 += c.y; s6 += d.x; s7 += d.y;
            }
        }
    }
    // full butterfly -> every lane holds the totals for its fb
#pragma unroll
    for (int m = 4; m <= 16; m <<= 1) {
        s0 += __shfl_xor(s0, m, 64); s1 += __shfl_xor(s1, m, 64);
        s2 += __shfl_xor(s2, m, 64); s3 += __shfl_xor(s3, m, 64);
        s4 += __shfl_xor(s4, m, 64); s5 += __shfl_xor(s5, m, 64);
        s6 += __shfl_xor(s6, m, 64); s7 += __shfl_xor(s7, m, 64);
    }
    float dn = dis[node];
    float4 hv = h4[(size_t)node * 4 + fb];   // self-loop: + h~[node]
    const __half2* hp = (const __half2*)&hv;
    float2 a = __half22float2(hp[0]);
    float2 b = __half22float2(hp[1]);
    float2 c = __half22float2(hp[2]);
    float2 d = __half22float2(hp[3]);
    const float4* bv4 = (const float4*)bias;
    float4 b0 = bv4[fb * 2], b1 = bv4[fb * 2 + 1];
    float o[8];
    o[0] = fmaxf(fmaf(dn, s0 + a.x, b0.x), 0.0f);
    o[1] = fmaxf(fmaf(dn, s1 + a.y, b0.y), 0.0f);
    o[2] = fmaxf(fmaf(dn, s2 + b.x, b0.z), 0.0f);
    o[3] = fmaxf(fmaf(dn, s3 + b.y, b0.w), 0.0f);
    o[4] = fmaxf(fmaf(dn, s4 + c.x, b1.x), 0.0f);
    o[5] = fmaxf(fmaf(dn, s5 + c.y, b1.y), 0.0f);
    o[6] = fmaxf(fmaf(dn, s6 + d.x, b1.z), 0.0f);
    o[7] = fmaxf(fmaf(dn, s7 + d.y, b1.w), 0.0f);
    // mm2: lane l32 computes output feature l32; feature k lives on lane k>>3
    // (lanes 0..3 are canonical holders for fb=0..3), reg k&7.
    float acc = 0.0f;
#pragma unroll
    for (int k = 0; k < FEAT; ++k)
        acc = fmaf(__shfl(o[k & 7], k >> 3, 32), Wl[k * FEAT + l32], acc);
    h2[(size_t)node * FEAT + l32] = __float2half(dn * acc);
}

// Final pull: out[d] = relu( dis[d] * (sum_{s in N(d)} h~[s] + h~[d]) + bias ).
__global__ __launch_bounds__(256, 6)
void pull_kernel(const int* __restrict__ recs, const int* __restrict__ row_start,
                 const __half* __restrict__ h, const float* __restrict__ dis,
                 const float* __restrict__ bias, float* __restrict__ out,
                 int n, int relu_out) {
    int t = threadIdx.x;
    int node = blockIdx.x * 8 + (t >> 5);
    if (node >= n) return;
    int l32 = t & 31;
    int sub = l32 >> 2;   // record slot 0..7
    int fb = l32 & 3;     // float4 feature block (8 halves)
    int start = row_start[node];
    int deg = row_start[node + 1] - start;
    const float4* h4 = (const float4*)h;  // 8 halves per float4, 4 per row
    float s0 = 0, s1 = 0, s2 = 0, s3 = 0, s4 = 0, s5 = 0, s6 = 0, s7 = 0;
    for (int r0 = 0; r0 < deg; r0 += 64) {
#pragma unroll
        for (int w = 0; w < 8; ++w) {
            int r = r0 + w * 8 + sub;
            if (r < deg) {
                int s = recs[start + r];
                float4 v = h4[(size_t)s * 4 + fb];
                const __half2* hp = (const __half2*)&v;
                float2 a = __half22float2(hp[0]);
                float2 b = __half22float2(hp[1]);
                float2 c = __half22float2(hp[2]);
                float2 d = __half22float2(hp[3]);
                s0 += a.x; s1 += a.y; s2 += b.x; s3 += b.y;
                s4 += c.x; s5 += c.y; s6 += d.x; s7 += d.y;
            }
        }
    }
#pragma unroll
    for (int m = 4; m <= 16; m <<= 1) {
        s0 += __shfl_xor(s0, m, 64); s1 += __shfl_xor(s1, m, 64);
        s2 += __shfl_xor(s2, m, 64); s3 += __shfl_xor(s3, m, 64);
        s4 += __shfl_xor(s4, m, 64); s5 += __shfl_xor(s5, m, 64);
        s6 += __shfl_xor(s6, m, 64); s7 += __shfl_xor(s7, m, 64);
    }
    if (sub == 0) {
        float dn = dis[node];
        float4 hv = h4[(size_t)node * 4 + fb];   // self-loop: + h~[node]
        const __half2* hp = (const __half2*)&hv;
        float2 a = __half22float2(hp[0]);
        float2 b = __half22float2(hp[1]);
        float2 c = __half22float2(hp[2]);
        float2 d = __half22float2(hp[3]);
        const float4* bv4 = (const float4*)bias;
        float4 b0 = bv4[fb * 2], b1 = bv4[fb * 2 + 1];
        float4 o0, o1;
        o0.x = fmaf(dn, s0 + a.x, b0.x);
        o0.y = fmaf(dn, s1 + a.y, b0.y);
        o0.z = fmaf(dn, s2 + b.x, b0.z);
        o0.w = fmaf(dn, s3 + b.y, b0.w);
        o1.x = fmaf(dn, s4 + c.x, b1.x);
        o1.y = fmaf(dn, s5 + c.y, b1.y);
        o1.z = fmaf(dn, s6 + d.x, b1.z);
        o1.w = fmaf(dn, s7 + d.y, b1.w);
        if (relu_out) {
            o0.x = fmaxf(o0.x, 0.0f); o0.y = fmaxf(o0.y, 0.0f);
            o0.z = fmaxf(o0.z, 0.0f); o0.w = fmaxf(o0.w, 0.0f);
            o1.x = fmaxf(o1.x, 0.0f); o1.y = fmaxf(o1.y, 0.0f);
            o1.z = fmaxf(o1.z, 0.0f); o1.w = fmaxf(o1.w, 0.0f);
        }
        ((float4*)out)[(size_t)node * 8 + fb * 2] = o0;
        ((float4*)out)[(size_t)node * 8 + fb * 2 + 1] = o1;
    }
}

extern "C" void kernel_launch(void* const* d_in, const int* in_sizes, int n_in,
                              void* d_out, int out_size, void* d_ws, size_t ws_size,
                              hipStream_t stream) {
    const float* x = (const float*)d_in[0];
    const void* eidx_raw = d_in[1];
    const float* W1 = (const float*)d_in[2];
    const float* b1 = (const float*)d_in[3];
    const float* W2 = (const float*)d_in[4];
    const float* b2 = (const float*)d_in[5];
    float* out = (float*)d_out;

    const int n = in_sizes[0] / FEAT;                    // 100000
    const int e = in_sizes[1] / 2;                       // 1600000
    const int nb = (n + BIN_NODES - 1) / BIN_NODES;      // 782
    const int nblk = (e + TILE_EDGES - 1) / TILE_EDGES;  // 196
    const int M = nb * nblk;                             // 153k
    const int nbks = (M + 255) / 256;                    // 599 <= 1024

    // Workspace (256B-aligned). `packed` aliases `h2` (packed dead after
    // degsort; h2 first written by pull_mm; both exactly e*4 == n*64 bytes).
    char* ws = (char*)d_ws;
    size_t off = 0;
    auto alloc = [&](size_t bytes) { char* p = ws + off; off = (off + bytes + 255) & ~(size_t)255; return p; };
    int*    mat       = (int*)   alloc((size_t)M * 4);
    int*    bsum      = (int*)   alloc((size_t)nbks * 4);
    float*  dis       = (float*) alloc((size_t)n * 4);
    int*    row_start = (int*)   alloc((size_t)(n + 1) * 4);
    int*    recs      = (int*)   alloc((size_t)e * 4);
    __half* h1        = (__half*)alloc((size_t)n * FEAT * 2);
    __half* h2        = (__half*)alloc((size_t)(n * FEAT * 2 > e * 4 ? (size_t)n * FEAT * 2 : (size_t)e * 4));
    int*    packed    = (int*)h2;

    const size_t ldsA = (size_t)(BWAVES * nb + 1) * 4;   // ~50 KB
    const size_t ldsC = (size_t)(nb + 1) * 4;            // ~3.1 KB
    const int gNode = (n + 7) / 8;

    // CSR build
    binA_kernel<<<nblk, 1024, ldsA, stream>>>(eidx_raw, mat, e, nb);
    scan1_kernel<<<nbks, 256, 0, stream>>>(mat, bsum, M, nb, nblk);
    scan2_kernel<<<1, 1024, 0, stream>>>(bsum, nbks);
    binC_kernel<<<nblk, 1024, ldsC, stream>>>(eidx_raw, mat, bsum, packed, e, nb, nblk);
    // degsort + fused layer-1 transform (x@W1 -> h1)
    degsort_kernel<<<nb, 1024, 0, stream>>>(packed, mat, bsum, dis, row_start,
                                            recs, x, W1, h1, e, n, nb, nblk);

    // Layer-1 aggregate + fused layer-2 transform (-> h2)
    pull_mm_kernel<<<gNode, 256, 0, stream>>>(recs, row_start, h1, dis, b1, W2, h2, n);
    // Layer-2 aggregate + bias + final relu
    pull_kernel<<<gNode, 256, 0, stream>>>(recs, row_start, h2, dis, b2, out, n, 1);
}

// Round 2
// 182.464 us; speedup vs baseline: 1.2465x; 1.1154x over previous
//
#include <hip/hip_runtime.h>
#include <hip/hip_fp16.h>

#define FEAT 32
#define BIN_NODES 128
#define BIN_SHIFT 7
#define TILE_EDGES 8192   // edges per build block
#define BWAVES 16         // waves per build block (1024 threads)
#define SRC_BITS 20
#define SRC_MASK 0xFFFFF

// Block-local int64-vs-int32 detection: odd 32-bit words of an int64 index
// array (values < 2^31) are all zero; for int32 they are random node ids.
__device__ __forceinline__ int block_detect_int64(const int* __restrict__ raw32, int* nz) {
    if (threadIdx.x == 0) *nz = 0;
    __syncthreads();
    if (raw32[2 * threadIdx.x + 1] != 0) *nz = 1;
    __syncthreads();
    return (*nz == 0) ? 1 : 0;
}

__device__ __forceinline__ int load_idx(const void* raw, int f, long long i) {
    return f ? (int)((const long long*)raw)[i] : ((const int*)raw)[i];
}

// Phase A: per-(tile,bin) histogram, 16 wave-private copies (1024 threads).
// mat layout: mat[k*nb + b] (tile-major). Writeout merges the 16 copies.
__global__ __launch_bounds__(1024)
void binA_kernel(const void* __restrict__ raw, int* __restrict__ mat, int e, int nb) {
    extern __shared__ int hist[];  // BWAVES*nb + 1
    int t = threadIdx.x;
    for (int i = t; i < BWAVES * nb; i += 1024) hist[i] = 0;
    int f = block_detect_int64((const int*)raw, &hist[BWAVES * nb]);
    int w = t >> 6, lane = t & 63;
    long long base = (long long)blockIdx.x * TILE_EDGES;
    int cnt = (int)min((long long)TILE_EDGES, (long long)e - base);
    int* hw = hist + w * nb;
    const int seg = TILE_EDGES / BWAVES;  // 512 edges per wave
    int wbeg = w * seg;
    int wend = min(wbeg + seg, cnt);
    for (int i = wbeg + lane; i < wend; i += 64) {
        int d = load_idx(raw, f, (long long)e + base + i);
        atomicAdd(&hw[d >> BIN_SHIFT], 1);
    }
    __syncthreads();
    for (int b = t; b < nb; b += 1024) {
        int s = 0;
#pragma unroll
        for (int w2 = 0; w2 < BWAVES; ++w2) s += hist[w2 * nb + b];
        mat[blockIdx.x * nb + b] = s;
    }
}

// logical L = b*nblk + k (bin-major) <-> physical p = k*nb + b
__device__ __forceinline__ int l2p(int L, int nb, int nblk) {
    int b = L / nblk;
    int k = L - b * nblk;
    return k * nb + b;
}

__global__ void scan1_kernel(int* __restrict__ mat, int* __restrict__ bsum,
                             int M, int nb, int nblk) {
    __shared__ int sd[256];
    int t = threadIdx.x;
    int L = blockIdx.x * 256 + t;
    int p = 0, v = 0;
    if (L < M) { p = l2p(L, nb, nblk); v = mat[p]; }
    sd[t] = v;
    __syncthreads();
    for (int off = 1; off < 256; off <<= 1) {
        int add = (t >= off) ? sd[t - off] : 0;
        __syncthreads();
        sd[t] += add;
        __syncthreads();
    }
    if (L < M) mat[p] = sd[t] - v;   // exclusive within scan-block
    if (t == 255) bsum[blockIdx.x] = sd[t];
}

__global__ void scan2_kernel(int* __restrict__ bsum, int nbks) {
    __shared__ int sd[1024];
    int t = threadIdx.x;
    int v = (t < nbks) ? bsum[t] : 0;
    sd[t] = v;
    __syncthreads();
    for (int off = 1; off < 1024; off <<= 1) {
        int add = (t >= off) ? sd[t - off] : 0;
        __syncthreads();
        sd[t] += add;
        __syncthreads();
    }
    if (t < nbks) bsum[t] = sd[t] - v;
}

// Phase C: scatter packed records grouped by bin (1024 threads; block-shared
// cursors — conflict cycles measured negligible). rec = src | dst_local<<20.
__global__ __launch_bounds__(1024)
void binC_kernel(const void* __restrict__ raw, const int* __restrict__ mat,
                 const int* __restrict__ bsum, int* __restrict__ packed,
                 int e, int nb, int nblk) {
    extern __shared__ int cur[];  // nb + 1
    int t = threadIdx.x;
    int f = block_detect_int64((const int*)raw, &cur[nb]);
    for (int i = t; i < nb; i += 1024)
        cur[i] = mat[blockIdx.x * nb + i] + bsum[(i * nblk + blockIdx.x) >> 8];
    __syncthreads();
    long long base = (long long)blockIdx.x * TILE_EDGES;
    int cnt = (int)min((long long)TILE_EDGES, (long long)e - base);
    for (int i = t; i < cnt; i += 1024) {
        long long ei = base + i;
        int s = load_idx(raw, f, ei);
        int d = load_idx(raw, f, (long long)e + ei);
        int b = d >> BIN_SHIFT;
        int pos = atomicAdd(&cur[b], 1);
        packed[pos] = s | ((d & (BIN_NODES - 1)) << SRC_BITS);
    }
}

// Per-bin: 16 wave-private LDS histograms -> scan -> dis/row_start + per-wave
// base cursors, then contention-free counting-sort (recs = src, 4B).
// FUSED layer-1 transform: h1[node] = fp16(dis*(x@W1)) with W1 in LDS.
__global__ __launch_bounds__(1024)
void degsort_kernel(const int* __restrict__ packed, const int* __restrict__ mat,
                    const int* __restrict__ bsum, float* __restrict__ dis,
                    int* __restrict__ row_start, int* __restrict__ recs,
                    const float* __restrict__ x, const float* __restrict__ W1,
                    __half* __restrict__ h1,
                    int e, int n, int nb, int nblk) {
    __shared__ int cnt[BWAVES][BIN_NODES];
    __shared__ int wcur[BWAVES][BIN_NODES];
    __shared__ int exc[BIN_NODES];
    __shared__ float sdis[BIN_NODES];
    __shared__ float W1l[FEAT * FEAT];
    int b = blockIdx.x, t = threadIdx.x;
    int w = t >> 6;
    for (int i = t; i < BWAVES * BIN_NODES; i += 1024) ((int*)cnt)[i] = 0;
    if (t < FEAT * FEAT) W1l[t] = W1[t];   // 1024 threads, 1024 elems
    __syncthreads();
    int start = mat[b] + bsum[(b * nblk) >> 8];
    int end = (b + 1 < nb) ? (mat[b + 1] + bsum[((b + 1) * nblk) >> 8]) : e;
    for (int i = start + t; i < end; i += 1024)
        atomicAdd(&cnt[w][packed[i] >> SRC_BITS], 1);
    __syncthreads();
    if (t < BIN_NODES) {
        int s = 0;
#pragma unroll
        for (int w2 = 0; w2 < BWAVES; ++w2) s += cnt[w2][t];
        exc[t] = s;
    }
    __syncthreads();
    for (int off = 1; off < BIN_NODES; off <<= 1) {
        int v = 0;
        if (t < BIN_NODES && t >= off) v = exc[t - off];
        __syncthreads();
        if (t < BIN_NODES) exc[t] += v;
        __syncthreads();
    }
    if (t < BIN_NODES) {
        int tot = 0;
#pragma unroll
        for (int w2 = 0; w2 < BWAVES; ++w2) tot += cnt[w2][t];
        int rs = start + exc[t] - tot;   // inclusive -> exclusive
        int run = rs;
#pragma unroll
        for (int w2 = 0; w2 < BWAVES; ++w2) { wcur[w2][t] = run; run += cnt[w2][t]; }
        float dv = rsqrtf((float)tot + 1.0f);
        sdis[t] = dv;
        int node = b * BIN_NODES + t;
        if (node < n) {
            dis[node] = dv;
            row_start[node] = rs;
        }
    }
    if (b == 0 && t == 128) row_start[n] = e;  // sentinel
    __syncthreads();
    for (int i = start + t; i < end; i += 1024) {
        int rec = packed[i];
        int pos = atomicAdd(&wcur[w][rec >> SRC_BITS], 1);
        recs[pos] = rec & SRC_MASK;
    }
    // fused mm1: 8 threads/node, each thread holds one float4 of the x-row and
    // produces 4 output features; 8-wide shfl broadcasts the x values.
    {
        int ln = b * BIN_NODES + (t >> 3);
        if (ln < n) {
            int q = t & 7;
            float4 xv = ((const float4*)x)[(size_t)ln * 8 + q];
            float xr[4] = {xv.x, xv.y, xv.z, xv.w};
            float o[4] = {0.f, 0.f, 0.f, 0.f};
#pragma unroll
            for (int k = 0; k < FEAT; ++k) {
                float xk = __shfl(xr[k & 3], k >> 2, 8);
#pragma unroll
                for (int c = 0; c < 4; ++c)
                    o[c] = fmaf(xk, W1l[k * FEAT + q * 4 + c], o[c]);
            }
            float dn = sdis[t >> 3];
            __half2* hp = (__half2*)&h1[(size_t)ln * FEAT + q * 4];
            hp[0] = __halves2half2(__float2half(dn * o[0]), __float2half(dn * o[1]));
            hp[1] = __halves2half2(__float2half(dn * o[2]), __float2half(dn * o[3]));
        }
    }
}

// Layer-1 pull FUSED with layer-2 transform, 16 lanes/node (4 slots x 4
// feature-quads): 4 gathers in flight per lane, 2-level slot butterfly, then
// mm2 as distributed 8x8 register blocks + 2-level fb butterfly (no serial
// shfl-fma chain). W2 staged in LDS with per-k-block column rotation so the
// 16-lane read pattern is bank-conflict-free.
__global__ __launch_bounds__(256, 6)
void pull_mm_kernel(const int* __restrict__ recs, const int* __restrict__ row_start,
                    const __half* __restrict__ h, const float* __restrict__ dis,
                    const float* __restrict__ bias, const float* __restrict__ W2,
                    __half* __restrict__ h2, int n) {
    __shared__ float Wl[FEAT * FEAT];
    int t = threadIdx.x;
    for (int i = t; i < FEAT * FEAT; i += 256) {
        int k = i >> 5, j = i & 31;
        int col = (j & 24) | ((j + 2 * (k >> 3)) & 7);   // rotate within 8-block
        Wl[k * FEAT + col] = W2[i];
    }
    __syncthreads();
    int node = blockIdx.x * 16 + (t >> 4);
    if (node >= n) return;
    int g = t & 15;
    int sub = g >> 2;   // record slot 0..3
    int fb = g & 3;     // float4 feature block (8 halves)
    int start = row_start[node];
    int deg = row_start[node + 1] - start;
    const float4* h4 = (const float4*)h;  // 8 halves per float4, 4 per row
    float s0 = 0, s1 = 0, s2 = 0, s3 = 0, s4 = 0, s5 = 0, s6 = 0, s7 = 0;
    for (int r0 = 0; r0 < deg; r0 += 32) {
#pragma unroll
        for (int w = 0; w < 8; ++w) {
            int r = r0 + w * 4 + sub;
            if (r < deg) {
                int s = recs[start + r];
                float4 v = h4[(size_t)s * 4 + fb];
                const __half2* hp = (const __half2*)&v;
                float2 a = __half22float2(hp[0]);
                float2 b = __half22float2(hp[1]);
                float2 c = __half22float2(hp[2]);
                float2 d = __half22float2(hp[3]);
                s0 += a.x; s1 += a.y; s2 += b.x; s3 += b.y;
                s4 += c.x; s5 += c.y; s6 += d.x; s7 += d.y;
            }
        }
    }
    // 2-level butterfly over slots (xor 4, 8) -> all 16 lanes hold fb totals
#pragma unroll
    for (int m = 4; m <= 8; m <<= 1) {
        s0 += __shfl_xor(s0, m, 64); s1 += __shfl_xor(s1, m, 64);
        s2 += __shfl_xor(s2, m, 64); s3 += __shfl_xor(s3, m, 64);
        s4 += __shfl_xor(s4, m, 64); s5 += __shfl_xor(s5, m, 64);
        s6 += __shfl_xor(s6, m, 64); s7 += __shfl_xor(s7, m, 64);
    }
    float dn = dis[node];
    float4 hv = h4[(size_t)node * 4 + fb];   // self-loop: + h~[node]
    const __half2* hp = (const __half2*)&hv;
    float2 a = __half22float2(hp[0]);
    float2 b = __half22float2(hp[1]);
    float2 c = __half22float2(hp[2]);
    float2 d = __half22float2(hp[3]);
    const float4* bv4 = (const float4*)bias;
    float4 b0 = bv4[fb * 2], b1 = bv4[fb * 2 + 1];
    float o[8];
    o[0] = fmaxf(fmaf(dn, s0 + a.x, b0.x), 0.0f);
    o[1] = fmaxf(fmaf(dn, s1 + a.y, b0.y), 0.0f);
    o[2] = fmaxf(fmaf(dn, s2 + b.x, b0.z), 0.0f);
    o[3] = fmaxf(fmaf(dn, s3 + b.y, b0.w), 0.0f);
    o[4] = fmaxf(fmaf(dn, s4 + c.x, b1.x), 0.0f);
    o[5] = fmaxf(fmaf(dn, s5 + c.y, b1.y), 0.0f);
    o[6] = fmaxf(fmaf(dn, s6 + d.x, b1.z), 0.0f);
    o[7] = fmaxf(fmaf(dn, s7 + d.y, b1.w), 0.0f);
    // mm2: lane (sub,fb) computes the 8x8 block k in [8fb,8fb+8) x j in
    // [8sub,8sub+8) of relu(out1) @ W2, entirely from registers + LDS.
    float part[8] = {0.f, 0.f, 0.f, 0.f, 0.f, 0.f, 0.f, 0.f};
    const float* wrow = &Wl[(fb * 8) * FEAT + sub * 8];
#pragma unroll
    for (int cc = 0; cc < 8; ++cc) {
#pragma unroll
        for (int c2 = 0; c2 < 8; ++c2)
            part[c2] = fmaf(o[cc], wrow[cc * FEAT + ((c2 + 2 * fb) & 7)], part[c2]);
    }
    // 2-level butterfly over fb (xor 1, 2) -> full k-sum for features 8sub+c2
#pragma unroll
    for (int m = 1; m <= 2; m <<= 1) {
        part[0] += __shfl_xor(part[0], m, 64); part[1] += __shfl_xor(part[1], m, 64);
        part[2] += __shfl_xor(part[2], m, 64); part[3] += __shfl_xor(part[3], m, 64);
        part[4] += __shfl_xor(part[4], m, 64); part[5] += __shfl_xor(part[5], m, 64);
        part[6] += __shfl_xor(part[6], m, 64); part[7] += __shfl_xor(part[7], m, 64);
    }
    if (fb == 0) {
        __half2 p0 = __halves2half2(__float2half(dn * part[0]), __float2half(dn * part[1]));
        __half2 p1 = __halves2half2(__float2half(dn * part[2]), __float2half(dn * part[3]));
        __half2 p2 = __halves2half2(__float2half(dn * part[4]), __float2half(dn * part[5]));
        __half2 p3 = __halves2half2(__float2half(dn * part[6]), __float2half(dn * part[7]));
        float4 pk;
        ((__half2*)&pk)[0] = p0; ((__half2*)&pk)[1] = p1;
        ((__half2*)&pk)[2] = p2; ((__half2*)&pk)[3] = p3;
        ((float4*)h2)[(size_t)node * 4 + sub] = pk;  // features 8sub..8sub+7
    }
}

// Final pull, 16 lanes/node: out[d] = relu( dis[d]*(sum h~[s] + h~[d]) + b ).
__global__ __launch_bounds__(256, 6)
void pull_kernel(const int* __restrict__ recs, const int* __restrict__ row_start,
                 const __half* __restrict__ h, const float* __restrict__ dis,
                 const float* __restrict__ bias, float* __restrict__ out, int n) {
    int t = threadIdx.x;
    int node = blockIdx.x * 16 + (t >> 4);
    if (node >= n) return;
    int g = t & 15;
    int sub = g >> 2;   // record slot 0..3
    int fb = g & 3;     // float4 feature block (8 halves)
    int start = row_start[node];
    int deg = row_start[node + 1] - start;
    const float4* h4 = (const float4*)h;  // 8 halves per float4, 4 per row
    float s0 = 0, s1 = 0, s2 = 0, s3 = 0, s4 = 0, s5 = 0, s6 = 0, s7 = 0;
    for (int r0 = 0; r0 < deg; r0 += 32) {
#pragma unroll
        for (int w = 0; w < 8; ++w) {
            int r = r0 + w * 4 + sub;
            if (r < deg) {
                int s = recs[start + r];
                float4 v = h4[(size_t)s * 4 + fb];
                const __half2* hp = (const __half2*)&v;
                float2 a = __half22float2(hp[0]);
                float2 b = __half22float2(hp[1]);
                float2 c = __half22float2(hp[2]);
                float2 d = __half22float2(hp[3]);
                s0 += a.x; s1 += a.y; s2 += b.x; s3 += b.y;
                s4 += c.x; s5 += c.y; s6 += d.x; s7 += d.y;
            }
        }
    }
#pragma unroll
    for (int m = 4; m <= 8; m <<= 1) {
        s0 += __shfl_xor(s0, m, 64); s1 += __shfl_xor(s1, m, 64);
        s2 += __shfl_xor(s2, m, 64); s3 += __shfl_xor(s3, m, 64);
        s4 += __shfl_xor(s4, m, 64); s5 += __shfl_xor(s5, m, 64);
        s6 += __shfl_xor(s6, m, 64); s7 += __shfl_xor(s7, m, 64);
    }
    if (sub == 0) {
        float dn = dis[node];
        float4 hv = h4[(size_t)node * 4 + fb];   // self-loop: + h~[node]
        const __half2* hp = (const __half2*)&hv;
        float2 a = __half22float2(hp[0]);
        float2 b = __half22float2(hp[1]);
        float2 c = __half22float2(hp[2]);
        float2 d = __half22float2(hp[3]);
        const float4* bv4 = (const float4*)bias;
        float4 b0 = bv4[fb * 2], b1 = bv4[fb * 2 + 1];
        float4 o0, o1;
        o0.x = fmaxf(fmaf(dn, s0 + a.x, b0.x), 0.0f);
        o0.y = fmaxf(fmaf(dn, s1 + a.y, b0.y), 0.0f);
        o0.z = fmaxf(fmaf(dn, s2 + b.x, b0.z), 0.0f);
        o0.w = fmaxf(fmaf(dn, s3 + b.y, b0.w), 0.0f);
        o1.x = fmaxf(fmaf(dn, s4 + c.x, b1.x), 0.0f);
        o1.y = fmaxf(fmaf(dn, s5 + c.y, b1.y), 0.0f);
        o1.z = fmaxf(fmaf(dn, s6 + d.x, b1.z), 0.0f);
        o1.w = fmaxf(fmaf(dn, s7 + d.y, b1.w), 0.0f);
        ((float4*)out)[(size_t)node * 8 + fb * 2] = o0;
        ((float4*)out)[(size_t)node * 8 + fb * 2 + 1] = o1;
    }
}

extern "C" void kernel_launch(void* const* d_in, const int* in_sizes, int n_in,
                              void* d_out, int out_size, void* d_ws, size_t ws_size,
                              hipStream_t stream) {
    const float* x = (const float*)d_in[0];
    const void* eidx_raw = d_in[1];
    const float* W1 = (const float*)d_in[2];
    const float* b1 = (const float*)d_in[3];
    const float* W2 = (const float*)d_in[4];
    const float* b2 = (const float*)d_in[5];
    float* out = (float*)d_out;

    const int n = in_sizes[0] / FEAT;                    // 100000
    const int e = in_sizes[1] / 2;                       // 1600000
    const int nb = (n + BIN_NODES - 1) / BIN_NODES;      // 782
    const int nblk = (e + TILE_EDGES - 1) / TILE_EDGES;  // 196
    const int M = nb * nblk;                             // 153k
    const int nbks = (M + 255) / 256;                    // 599 <= 1024

    // Workspace (256B-aligned). `packed` aliases `h2` (packed dead after
    // degsort; h2 first written by pull_mm; both exactly e*4 == n*64 bytes).
    char* ws = (char*)d_ws;
    size_t off = 0;
    auto alloc = [&](size_t bytes) { char* p = ws + off; off = (off + bytes + 255) & ~(size_t)255; return p; };
    int*    mat       = (int*)   alloc((size_t)M * 4);
    int*    bsum      = (int*)   alloc((size_t)nbks * 4);
    float*  dis       = (float*) alloc((size_t)n * 4);
    int*    row_start = (int*)   alloc((size_t)(n + 1) * 4);
    int*    recs      = (int*)   alloc((size_t)e * 4);
    __half* h1        = (__half*)alloc((size_t)n * FEAT * 2);
    __half* h2        = (__half*)alloc((size_t)(n * FEAT * 2 > e * 4 ? (size_t)n * FEAT * 2 : (size_t)e * 4));
    int*    packed    = (int*)h2;

    const size_t ldsA = (size_t)(BWAVES * nb + 1) * 4;   // ~50 KB
    const size_t ldsC = (size_t)(nb + 1) * 4;            // ~3.1 KB
    const int gNode = (n + 15) / 16;

    // CSR build
    binA_kernel<<<nblk, 1024, ldsA, stream>>>(eidx_raw, mat, e, nb);
    scan1_kernel<<<nbks, 256, 0, stream>>>(mat, bsum, M, nb, nblk);
    scan2_kernel<<<1, 1024, 0, stream>>>(bsum, nbks);
    binC_kernel<<<nblk, 1024, ldsC, stream>>>(eidx_raw, mat, bsum, packed, e, nb, nblk);
    // degsort + fused layer-1 transform (x@W1 -> h1)
    degsort_kernel<<<nb, 1024, 0, stream>>>(packed, mat, bsum, dis, row_start,
                                            recs, x, W1, h1, e, n, nb, nblk);

    // Layer-1 aggregate + fused layer-2 transform (-> h2)
    pull_mm_kernel<<<gNode, 256, 0, stream>>>(recs, row_start, h1, dis, b1, W2, h2, n);
    // Layer-2 aggregate + bias + final relu
    pull_kernel<<<gNode, 256, 0, stream>>>(recs, row_start, h2, dis, b2, out, n);
}